// Round 9
// baseline (180.848 us; speedup 1.0000x reference)
//
#include <hip/hip_runtime.h>
#include <math.h>

#define LTOK 4096
#define EDIM 512
#define SDIM 1024
#define HDIM 150
#define SEG 160            // padded segment width (cols) and P-row stride
#define MAXN 10
#define TOTAL_ROWS 40915   // sum_{n=1..10} (L - n + 1)
#define KA 1536            // padded K: 1024 states + 512 embeds
#define NKT 48             // k-tiles of 32
#define K2 160             // padded K and N for 150x150 layers
#define NCG 42             // packed-W col groups: P1(0-9)|P2(10-19)|PE(20-29)|pad(30-31)|attn(32-41)

typedef _Float16 hfrag __attribute__((ext_vector_type(8)));  // 8 fp16, 4 VGPRs
typedef float ffrag __attribute__((ext_vector_type(4)));     // MFMA C/D

#define MFMA_(a, b, c) __builtin_amdgcn_mfma_f32_16x16x32_f16(a, b, c, 0, 0, 0)

// Packed-fragment layouts (fp16):
//   Apk [(g*48 + kt)*64 + lane][8]   : A[row=g*16+l16][k=kt*32+quad*8+j]
//   Wpk [(cg*48 + kt)*64 + lane][8]  : W[col=cg*16+l16][k...]
//   W2pk/A2pk [(ct*5+ks)*64 + lane][8]
// Column map (col = cg*16 + l16):
//   [0,160)  P1  (cj=col,     k<1024,  sW1 rows 0..1023)
//   [160,320) P2 (cj=col-160, k<1024,  sW1 rows 1024..2047)
//   [320,480) PE (cj=col-320, k>=1024, sW1 rows 2048..2559)
//   [480,512) zero pad  (prep writes ZEROS here and outside each segment's
//                        live k-range -> union-K MFMAs add exact +0)
//   [512,672) attn (cj=col-512, k<1024, aW1)

#define ITEMS_A   (LTOK * (KA / 8))   // 786432
#define ITEMS_W   (NCG * NKT * 64)    // 129024
#define ITEMS_W2  (K2 * (K2 / 8))     // 3200 (sW2)
#define ITEMS_A2  (K2 * (K2 / 8))     // 3200 (aW2)
#define ITEMS_TOT (ITEMS_A + ITEMS_W + ITEMS_W2 + ITEMS_A2)   // 921856 = 3601*256

// ---------------------------------------------------------------------------
// prep: fp32 -> fp16 conversion + MFMA-fragment packing (coalesced streams).
// ---------------------------------------------------------------------------
__global__ __launch_bounds__(256) void prep_kernel(
    const float* __restrict__ embeds, const float* __restrict__ states,
    const float* __restrict__ aW1, const float* __restrict__ aW2,
    const float* __restrict__ sW1, const float* __restrict__ sW2,
    _Float16* __restrict__ Apk, _Float16* __restrict__ Wpk,
    _Float16* __restrict__ W2pk, _Float16* __restrict__ A2pk)
{
    int it = blockIdx.x * 256 + threadIdx.x;
    if (it < ITEMS_A) {
        const int rem = it % (NKT * 64);
        const int g = it / (NKT * 64), kt = rem >> 6, lane = rem & 63;
        const int row = g * 16 + (lane & 15);
        const int k0 = kt * 32 + (lane >> 4) * 8;
        const float* src = (k0 < SDIM) ? (states + (size_t)row * SDIM + k0)
                                       : (embeds + (size_t)row * EDIM + (k0 - SDIM));
        const float4 v0 = *(const float4*)src;
        const float4 v1 = *(const float4*)(src + 4);
        _Float16 o[8] = {(_Float16)v0.x, (_Float16)v0.y, (_Float16)v0.z, (_Float16)v0.w,
                         (_Float16)v1.x, (_Float16)v1.y, (_Float16)v1.z, (_Float16)v1.w};
        *(uint4*)(Apk + (size_t)it * 8) = *(uint4*)o;
        return;
    }
    it -= ITEMS_A;
    if (it < ITEMS_W) {
        const int rem = it % (NKT * 64);
        const int cgi = it / (NKT * 64), kt = rem >> 6, lane = rem & 63;
        const int col = cgi * 16 + (lane & 15);
        const int k0 = kt * 32 + (lane >> 4) * 8;
        _Float16 o[8];
        for (int j = 0; j < 8; ++j) {
            const int k = k0 + j;
            float wv = 0.f;
            if (col < 160) {
                if (col < HDIM && k < SDIM) wv = sW1[(size_t)k * HDIM + col];
            } else if (col < 320) {
                const int cj = col - 160;
                if (cj < HDIM && k < SDIM) wv = sW1[(size_t)(SDIM + k) * HDIM + cj];
            } else if (col < 480) {
                const int cj = col - 320;
                if (cj < HDIM && k >= SDIM) wv = sW1[(size_t)(SDIM + k) * HDIM + cj]; // rows 2048+(k-1024)
            } else if (col >= 512) {
                const int cj = col - 512;
                if (cj < HDIM && k < SDIM) wv = aW1[(size_t)k * HDIM + cj];
            }
            o[j] = (_Float16)wv;
        }
        *(uint4*)(Wpk + ((size_t)((size_t)cgi * NKT + kt) * 64 + lane) * 8) = *(uint4*)o;
        return;
    }
    it -= ITEMS_W;
    if (it < ITEMS_W2 + ITEMS_A2) {
        const bool is_a = (it >= ITEMS_W2);
        const int li = is_a ? (it - ITEMS_W2) : it;
        const float* src = is_a ? aW2 : sW2;
        _Float16* dst = is_a ? A2pk : W2pk;
        const int tk = li >> 6, lane = li & 63;          // tk = ct*5+ks (0..49)
        const int col = (tk / 5) * 16 + (lane & 15);
        const int k0 = (tk % 5) * 32 + (lane >> 4) * 8;
        _Float16 o[8];
        for (int j = 0; j < 8; ++j) {
            const int k = k0 + j;
            float wv = (col < HDIM && k < HDIM) ? src[(size_t)k * HDIM + col] : 0.f;
            o[j] = (_Float16)wv;
        }
        *(uint4*)(dst + ((size_t)tk * 64 + lane) * 8) = *(uint4*)o;
    }
}

// ---------------------------------------------------------------------------
// k_proj (R9): cooperative LDS-staged tiles to cut L2/L3 traffic ~3x.
// Grid = 192: bid%3==0 -> attn block (64 tokens, B-panel LDS-staged, shared
// by 4 waves: attn B traffic 82->20 MB); else main block 128x128 (8rg x 8cg),
// BK=64 (2 kt), double-buffered LDS (64 KB), reg-staged prefetch 1.5 steps
// ahead, ONE barrier per step. Mixed-K col-tiles (bN2) run the union kt
// range: Wpk zeros make the extra MFMAs exact no-ops. Same per-acc kt order
// as R4..R8 -> bit-identical outputs.
// ---------------------------------------------------------------------------
__global__ __launch_bounds__(256) void k_proj(
    const _Float16* __restrict__ Apk, const _Float16* __restrict__ Wpk,
    const _Float16* __restrict__ A2pk,
    const float* __restrict__ ab1, const float* __restrict__ ab2,
    const float* __restrict__ aW3, const float* __restrict__ ab3,
    _Float16* __restrict__ P1h, _Float16* __restrict__ P2h,
    _Float16* __restrict__ PEh, float* __restrict__ attns)
{
    const int bid = blockIdx.x;
    const int tid = threadIdx.x;
    const int w = tid >> 6, lane = tid & 63;
    const int quad = lane >> 4, l16 = lane & 15;

    // 64 KB pool. main: 2 bufs x 16384 halfs (A 16 chunks | B 16 chunks).
    // attn: 2 bufs x 10240 halfs (B 20 chunks) + ah1[10240] at 20480.
    __shared__ __align__(16) _Float16 smem[32768];

    if (bid % 3 == 0) {
        // ---------------- attention scorer, 64 tokens ----------------
        const int tok0 = (bid / 3) * 64;
        const int g0 = tok0 >> 4;                      // row-groups g0..g0+3

        ffrag acc[10];
#pragma unroll
        for (int c = 0; c < 10; ++c) acc[c] = (ffrag){0.f, 0.f, 0.f, 0.f};

        // B staging: 20 chunks (cg' 0..9 x ktl 0..1); wave w -> chunks w*5+i
        const _Float16* bsrc[5];
        int bdst[5];
#pragma unroll
        for (int i = 0; i < 5; ++i) {
            const int c = w * 5 + i;
            const int cgp = c >> 1, ktl = c & 1;
            bsrc[i] = Wpk + ((size_t)(32 + cgp) * NKT + ktl) * 512 + lane * 8;
            bdst[i] = c * 512 + lane * 8;
        }
        // A: per-wave from global (rg = w), tiny traffic (8 MB total)
        const _Float16* asrc = Apk + ((size_t)(g0 + w) * NKT) * 512 + lane * 8;

        uint4 q[5];
#define LOADQ_A(ks)                                                         \
        _Pragma("unroll")                                                   \
        for (int i = 0; i < 5; ++i)                                         \
            q[i] = *(const uint4*)(bsrc[i] + (size_t)(ks) * 1024);
#define WRITEQ_A(bf)                                                        \
        _Pragma("unroll")                                                   \
        for (int i = 0; i < 5; ++i)                                         \
            *(uint4*)(smem + (bf) * 10240 + bdst[i]) = q[i];

        LOADQ_A(0);
        WRITEQ_A(0);
        LOADQ_A(1);
        __syncthreads();
        int buf = 0;
        for (int ks = 0; ks < 16; ++ks) {              // kt = 2*ks + ktl
            if (ks + 1 < 16) WRITEQ_A(buf ^ 1);
            if (ks + 2 < 16) LOADQ_A(ks + 2);
            const _Float16* Bb = smem + buf * 10240;
#pragma unroll
            for (int ktl = 0; ktl < 2; ++ktl) {
                const hfrag a = *(const hfrag*)(asrc + (size_t)(ks * 2 + ktl) * 512);
#pragma unroll
                for (int c = 0; c < 10; ++c) {
                    const hfrag b = *(const hfrag*)(Bb + (c * 2 + ktl) * 512 + lane * 8);
                    acc[c] = MFMA_(a, b, acc[c]);
                }
            }
            __syncthreads();
            buf ^= 1;
        }
#undef LOADQ_A
#undef WRITEQ_A

        // layer1 epilogue -> ah1 (relu + bias)
        _Float16* ah1 = smem + 20480;
#pragma unroll
        for (int c = 0; c < 10; ++c) {
            const int col = c * 16 + l16;
            const float b1 = (col < HDIM) ? ab1[col] : 0.f;
#pragma unroll
            for (int r = 0; r < 4; ++r) {
                const int row = w * 16 + quad * 4 + r;
                ah1[row * SEG + col] = (_Float16)fmaxf(acc[c][r] + b1, 0.f);
            }
        }
        __syncthreads();

        // layers 2+3: wave w -> its 16 tokens
        hfrag af[5];
#pragma unroll
        for (int ks = 0; ks < 5; ++ks)
            af[ks] = *(const hfrag*)&ah1[(w * 16 + l16) * SEG + ks * 32 + quad * 8];

        float part[4] = {0.f, 0.f, 0.f, 0.f};
        for (int ct = 0; ct < 10; ++ct) {
            ffrag a2 = (ffrag){0.f, 0.f, 0.f, 0.f};
#pragma unroll
            for (int ks = 0; ks < 5; ++ks) {
                const hfrag fb = *(const hfrag*)(
                    A2pk + ((size_t)(ct * 5 + ks) * 64 + lane) * 8);
                a2 = MFMA_(af[ks], fb, a2);
            }
            const int col = ct * 16 + l16;
            const float s2 = (col < HDIM) ? ab2[col] : 0.f;
            const float s3 = (col < HDIM) ? aW3[col] : 0.f;
#pragma unroll
            for (int r = 0; r < 4; ++r) part[r] += fmaxf(a2[r] + s2, 0.f) * s3;
        }
#pragma unroll
        for (int off = 1; off < 16; off <<= 1) {
#pragma unroll
            for (int r = 0; r < 4; ++r) part[r] += __shfl_xor(part[r], off, 64);
        }
        if (l16 == 0) {
            const float b3 = ab3[0];
#pragma unroll
            for (int r = 0; r < 4; ++r)
                attns[tok0 + w * 16 + quad * 4 + r] = part[r] + b3;
        }
        return;
    }

    // ---------------- main projection: 128x128 block, LDS dbuf ------------
    const int t = bid - bid / 3 - 1;                   // [0, 128)
    const int bN = t & 3, bM = t >> 2;                 // bN 0..3, bM 0..31
    const int g0 = bM * 8;                             // 8 row-groups
    const int cg0 = bN * 8;                            // 8 col-groups
    const int ksBeg = (bN == 3) ? 16 : 0;              // PE-only tile: kt>=32
    const int ksEnd = (bN >= 2) ? 24 : 16;             // union range for bN2

    ffrag acc[8][2];
#pragma unroll
    for (int rg = 0; rg < 8; ++rg)
#pragma unroll
        for (int u = 0; u < 2; ++u) acc[rg][u] = (ffrag){0.f, 0.f, 0.f, 0.f};

    // staging: 32 chunks/step (c<16: A rg=c>>1; else B cg=(c-16)>>1; ktl=c&1)
    // wave w stages chunks c = w*8 + i
    const _Float16* src[8];
    int dstc[8];
#pragma unroll
    for (int i = 0; i < 8; ++i) {
        const int c = w * 8 + i;
        const int ktl = c & 1;
        dstc[i] = c * 512 + lane * 8;
        if (c < 16) {
            const int rg = c >> 1;
            src[i] = Apk + ((size_t)(g0 + rg) * NKT + ktl) * 512 + lane * 8;
        } else {
            const int cg = (c - 16) >> 1;
            src[i] = Wpk + ((size_t)(cg0 + cg) * NKT + ktl) * 512 + lane * 8;
        }
    }

    uint4 q[8];
#define LOADQ_M(ks)                                                         \
    _Pragma("unroll")                                                       \
    for (int i = 0; i < 8; ++i)                                             \
        q[i] = *(const uint4*)(src[i] + (size_t)(ks) * 1024);
#define WRITEQ_M(bf)                                                        \
    _Pragma("unroll")                                                       \
    for (int i = 0; i < 8; ++i)                                             \
        *(uint4*)(smem + (bf) * 16384 + dstc[i]) = q[i];

    LOADQ_M(ksBeg);
    WRITEQ_M(0);
    if (ksBeg + 1 < ksEnd) LOADQ_M(ksBeg + 1);
    __syncthreads();
    int buf = 0;
    for (int ks = ksBeg; ks < ksEnd; ++ks) {
        if (ks + 1 < ksEnd) WRITEQ_M(buf ^ 1);         // q holds step ks+1
        if (ks + 2 < ksEnd) LOADQ_M(ks + 2);           // prefetch 1.5 ahead
        const _Float16* Ab = smem + buf * 16384;
        const _Float16* Bb = Ab + 8192;
#pragma unroll
        for (int ktl = 0; ktl < 2; ++ktl) {
            hfrag a[8], b[2];
#pragma unroll
            for (int rg = 0; rg < 8; ++rg)
                a[rg] = *(const hfrag*)(Ab + (rg * 2 + ktl) * 512 + lane * 8);
#pragma unroll
            for (int u = 0; u < 2; ++u)
                b[u] = *(const hfrag*)(Bb + ((w * 2 + u) * 2 + ktl) * 512 + lane * 8);
#pragma unroll
            for (int rg = 0; rg < 8; ++rg)
#pragma unroll
                for (int u = 0; u < 2; ++u)
                    acc[rg][u] = MFMA_(a[rg], b[u], acc[rg][u]);
        }
        __syncthreads();
        buf ^= 1;
    }
#undef LOADQ_M
#undef WRITEQ_M

#pragma unroll
    for (int rg = 0; rg < 8; ++rg)
#pragma unroll
        for (int u = 0; u < 2; ++u) {
            const int col = (cg0 + w * 2 + u) * 16 + l16;
#pragma unroll
            for (int r = 0; r < 4; ++r) {
                const int row = (g0 + rg) * 16 + quad * 4 + r;
                const _Float16 hv = (_Float16)acc[rg][u][r];
                if (col < 160)      P1h[(size_t)row * SEG + col] = hv;
                else if (col < 320) P2h[(size_t)row * SEG + (col - 160)] = hv;
                else if (col < 480) PEh[(size_t)row * SEG + (col - 320)] = hv;
                // col >= 480: zero-pad col-groups, skip
            }
        }
}

// ---------------------------------------------------------------------------
// span (n-paired, interleaved): pairI = bid % 5, mChunk = bid / 5. Handles
// n0=2*pairI+1 and n1=n0+1 for 32 m-values, sharing P1/PE loads. The 41
// unique PE rows (clamped) are staged once in LDS. PE loop fully unrolled
// to MAXN with zero weights past n (exact no-op fmaf).
// ---------------------------------------------------------------------------
__global__ __launch_bounds__(256) void span_kernel(
    const float* __restrict__ attns, const _Float16* __restrict__ P1h,
    const _Float16* __restrict__ P2h, const _Float16* __restrict__ PEh,
    const float* __restrict__ sb1, const _Float16* __restrict__ W2pk,
    const float* __restrict__ sb2, const float* __restrict__ sW3,
    const float* __restrict__ sb3, float* __restrict__ out)
{
    const int pairI = blockIdx.x % 5;         // 0..4 (interleaved heavy/light)
    const int mChunk = blockIdx.x / 5;        // 0..127
    const int n0 = 2 * pairI + 1, n1 = n0 + 1;
    const int Mn0 = LTOK - n0 + 1, Mn1 = Mn0 - 1;
    const int m0 = mChunk * 32;
    const int offn0 = (n0 - 1) * LTOK - ((n0 - 1) * (n0 - 2)) / 2;
    const int offn1 = offn0 + Mn0;

    const int tid = threadIdx.x;
    const int w = tid >> 6, lane = tid & 63, quad = lane >> 4, l16 = lane & 15;

    __shared__ __align__(16) _Float16 h1h[2][32 * K2];
    __shared__ __align__(16) _Float16 PEs[41 * SEG];   // staged PE rows (13 KB)
    __shared__ float wgt[2][32][MAXN];

    // stage PE rows m0..m0+40 (row-clamped) into LDS
    for (int t = tid; t < 41 * (SEG / 8); t += 256) {
        const int rr = t / (SEG / 8), cc = t % (SEG / 8);
        const int srcRow = min(m0 + rr, LTOK - 1);
        *(uint4*)&PEs[rr * SEG + cc * 8] =
            *(const uint4*)(PEh + (size_t)srcRow * SEG + cc * 8);
    }

    if (tid < 64) {
        const int q = tid >> 5, r = tid & 31;
        const int n = q ? n1 : n0;
        const int Mn = q ? Mn1 : Mn0;
        const int m = m0 + r;
        if (m < Mn) {
            float av[MAXN];
#pragma unroll
            for (int j = 0; j < MAXN; ++j)
                av[j] = attns[min(m + j, LTOK - 1)];   // parallel clamped loads
            float mx = -1e30f;
            for (int j = 0; j < n; ++j) mx = fmaxf(mx, av[j]);
            float tp[MAXN]; float s = 0.f;
            for (int j = 0; j < n; ++j) { tp[j] = expf(av[j] - mx); s += tp[j]; }
            const float inv = 1.f / s;
            for (int j = 0; j < MAXN; ++j) wgt[q][r][j] = (j < n) ? tp[j] * inv : 0.f;
        } else {
            for (int j = 0; j < MAXN; ++j) wgt[q][r][j] = 0.f;
        }
    }
    __syncthreads();

    // phase 1: 32 rows x 20 col-chunks (8 cols), BOTH n per item; full unroll
    for (int item = tid; item < 32 * (K2 / 8); item += 256) {
        const int r = item / (K2 / 8), cc = item % (K2 / 8);
        const int c0 = cc * 8;
        const int mm = m0 + r;                       // < 4096 always
        const hfrag p1  = *(const hfrag*)(P1h + (size_t)mm * SEG + c0);
        const hfrag p2a = *(const hfrag*)(P2h + (size_t)min(mm + n0 - 1, LTOK - 1) * SEG + c0);
        const hfrag p2b = *(const hfrag*)(P2h + (size_t)min(mm + n0, LTOK - 1) * SEG + c0);
        float b1v[8];
#pragma unroll
        for (int e = 0; e < 8; ++e)
            b1v[e] = (c0 + e < HDIM) ? sb1[c0 + e] : 0.f;
        float a0[8], a1[8];
#pragma unroll
        for (int e = 0; e < 8; ++e) {
            a0[e] = (float)p1[e] + (float)p2a[e] + b1v[e];
            a1[e] = (float)p1[e] + (float)p2b[e] + b1v[e];
        }
#pragma unroll
        for (int j = 0; j < MAXN; ++j) {             // weights 0 past n -> exact no-op
            const hfrag pe = *(const hfrag*)&PEs[(r + j) * SEG + c0];
            const float w0j = wgt[0][r][j];
            const float w1j = wgt[1][r][j];
#pragma unroll
            for (int e = 0; e < 8; ++e) {
                const float pv = (float)pe[e];
                a0[e] = fmaf(w0j, pv, a0[e]);
                a1[e] = fmaf(w1j, pv, a1[e]);
            }
        }
        _Float16 o0[8], o1[8];
#pragma unroll
        for (int e = 0; e < 8; ++e) {
            const bool live = (c0 + e < HDIM);
            o0[e] = live ? (_Float16)fmaxf(a0[e], 0.f) : (_Float16)0.f;
            o1[e] = live ? (_Float16)fmaxf(a1[e], 0.f) : (_Float16)0.f;
        }
        *(uint4*)&h1h[0][r * K2 + c0] = *(uint4*)o0;
        *(uint4*)&h1h[1][r * K2 + c0] = *(uint4*)o1;
    }
    __syncthreads();

    // phase 2: wave w -> side q = w>>1, row-group rg = w&1 (16 rows)
    const int q = w >> 1, rg = w & 1;
    const int Mq = q ? Mn1 : Mn0;
    const int offq = q ? offn1 : offn0;

    hfrag af[5];
#pragma unroll
    for (int ks = 0; ks < 5; ++ks)
        af[ks] = *(const hfrag*)&h1h[q][(rg * 16 + l16) * K2 + ks * 32 + quad * 8];

    float part[4] = {0.f, 0.f, 0.f, 0.f};
    for (int ct = 0; ct < 10; ++ct) {
        ffrag acc = (ffrag){0.f, 0.f, 0.f, 0.f};
#pragma unroll
        for (int ks = 0; ks < 5; ++ks) {
            const hfrag fb = *(const hfrag*)(
                W2pk + ((size_t)(ct * 5 + ks) * 64 + lane) * 8);
            acc = MFMA_(af[ks], fb, acc);
        }
        const int col = ct * 16 + l16;
        const float s2 = (col < HDIM) ? sb2[col] : 0.f;
        const float s3 = (col < HDIM) ? sW3[col] : 0.f;
#pragma unroll
        for (int r = 0; r < 4; ++r) part[r] += fmaxf(acc[r] + s2, 0.f) * s3;
    }

#pragma unroll
    for (int off = 1; off < 16; off <<= 1) {
#pragma unroll
        for (int r = 0; r < 4; ++r) part[r] += __shfl_xor(part[r], off, 64);
    }
    if (l16 == 0) {
        const float b3 = sb3[0];
#pragma unroll
        for (int r = 0; r < 4; ++r) {
            const int lr = rg * 16 + quad * 4 + r;   // 0..31
            if (m0 + lr < Mq) out[offq + m0 + lr] = part[r] + b3;
        }
    }
}

// ---------------------------------------------------------------------------
extern "C" void kernel_launch(void* const* d_in, const int* in_sizes, int n_in,
                              void* d_out, int out_size, void* d_ws, size_t ws_size,
                              hipStream_t stream) {
    const float* embeds = (const float*)d_in[0];
    const float* states = (const float*)d_in[1];
    const float* aW1 = (const float*)d_in[2];
    const float* ab1 = (const float*)d_in[3];
    const float* aW2 = (const float*)d_in[4];
    const float* ab2 = (const float*)d_in[5];
    const float* aW3 = (const float*)d_in[6];
    const float* ab3 = (const float*)d_in[7];
    const float* sW1 = (const float*)d_in[8];
    const float* sb1 = (const float*)d_in[9];
    const float* sW2 = (const float*)d_in[10];
    const float* sb2 = (const float*)d_in[11];
    const float* sW3 = (const float*)d_in[12];
    const float* sb3 = (const float*)d_in[13];
    float* out = (float*)d_out;

    // ws: fp32 attns | fp16 P1h | P2h | PEh (SEG rows) | Apk | Wpk | W2pk | A2pk
    float* attns = (float*)d_ws;
    _Float16* P1h  = (_Float16*)(attns + LTOK);
    _Float16* P2h  = P1h + (size_t)LTOK * SEG;
    _Float16* PEh  = P2h + (size_t)LTOK * SEG;
    _Float16* Apk  = PEh + (size_t)LTOK * SEG;
    _Float16* Wpk  = Apk + (size_t)ITEMS_A * 8;
    _Float16* W2pk = Wpk + (size_t)ITEMS_W * 8;
    _Float16* A2pk = W2pk + (size_t)ITEMS_W2 * 8;
    // total ~19 MB

    prep_kernel<<<ITEMS_TOT / 256, 256, 0, stream>>>(
        embeds, states, aW1, aW2, sW1, sW2, Apk, Wpk, W2pk, A2pk);
    k_proj<<<192, 256, 0, stream>>>(
        Apk, Wpk, A2pk, ab1, ab2, aW3, ab3, P1h, P2h, PEh, attns);
    span_kernel<<<640, 256, 0, stream>>>(
        attns, P1h, P2h, PEh, sb1, W2pk, sb2, sW3, sb3, out);
}

// Round 10
// 144.906 us; speedup vs baseline: 1.2480x; 1.2480x over previous
//
#include <hip/hip_runtime.h>
#include <math.h>

#define LTOK 4096
#define EDIM 512
#define SDIM 1024
#define HDIM 150
#define SEG 160            // padded segment width (cols) and P-row stride
#define MAXN 10
#define TOTAL_ROWS 40915   // sum_{n=1..10} (L - n + 1)
#define KA 1536            // padded K: 1024 states + 512 embeds
#define NKT 48             // k-tiles of 32
#define K2 160             // padded K and N for 150x150 layers
#define NCG 42             // packed-W col groups: P1(0-9)|P2(10-19)|PE(20-29)|pad(30-31)|attn(32-41)

typedef _Float16 hfrag __attribute__((ext_vector_type(8)));  // 8 fp16, 4 VGPRs
typedef float ffrag __attribute__((ext_vector_type(4)));     // MFMA C/D

#define MFMA_(a, b, c) __builtin_amdgcn_mfma_f32_16x16x32_f16(a, b, c, 0, 0, 0)

// Packed-fragment layouts (fp16):
//   Apk [(g*48 + kt)*64 + lane][8]   : A[row=g*16+l16][k=kt*32+quad*8+j]
//   Wpk [(cg*48 + kt)*64 + lane][8]  : W[col=cg*16+l16][k...]
//   W2pk/A2pk [(ct*5+ks)*64 + lane][8]
// Column map (col = cg*16 + l16):
//   [0,160)  P1  (cj=col,     k<1024,  sW1 rows 0..1023)
//   [160,320) P2 (cj=col-160, k<1024,  sW1 rows 1024..2047)
//   [320,480) PE (cj=col-320, k>=1024, sW1 rows 2048..2559)
//   [480,512) zero pad  (prep writes ZEROS outside each segment's live
//                        k-range -> union-K MFMAs add exact +0)
//   [512,672) attn (cj=col-512, k<1024, aW1)
// Live col-group list (40): cgl 0..29 -> cg 0..29; cgl 30..39 -> cg 32..41.

#define ITEMS_A   (LTOK * (KA / 8))   // 786432
#define ITEMS_W   (NCG * NKT * 64)    // 129024
#define ITEMS_W2  (K2 * (K2 / 8))     // 3200 (sW2)
#define ITEMS_A2  (K2 * (K2 / 8))     // 3200 (aW2)
#define ITEMS_TOT (ITEMS_A + ITEMS_W + ITEMS_W2 + ITEMS_A2)   // 921856 = 3601*256

// ---------------------------------------------------------------------------
// prep: fp32 -> fp16 conversion + MFMA-fragment packing (coalesced streams).
// ---------------------------------------------------------------------------
__global__ __launch_bounds__(256) void prep_kernel(
    const float* __restrict__ embeds, const float* __restrict__ states,
    const float* __restrict__ aW1, const float* __restrict__ aW2,
    const float* __restrict__ sW1, const float* __restrict__ sW2,
    _Float16* __restrict__ Apk, _Float16* __restrict__ Wpk,
    _Float16* __restrict__ W2pk, _Float16* __restrict__ A2pk)
{
    int it = blockIdx.x * 256 + threadIdx.x;
    if (it < ITEMS_A) {
        const int rem = it % (NKT * 64);
        const int g = it / (NKT * 64), kt = rem >> 6, lane = rem & 63;
        const int row = g * 16 + (lane & 15);
        const int k0 = kt * 32 + (lane >> 4) * 8;
        const float* src = (k0 < SDIM) ? (states + (size_t)row * SDIM + k0)
                                       : (embeds + (size_t)row * EDIM + (k0 - SDIM));
        const float4 v0 = *(const float4*)src;
        const float4 v1 = *(const float4*)(src + 4);
        _Float16 o[8] = {(_Float16)v0.x, (_Float16)v0.y, (_Float16)v0.z, (_Float16)v0.w,
                         (_Float16)v1.x, (_Float16)v1.y, (_Float16)v1.z, (_Float16)v1.w};
        *(uint4*)(Apk + (size_t)it * 8) = *(uint4*)o;
        return;
    }
    it -= ITEMS_A;
    if (it < ITEMS_W) {
        const int rem = it % (NKT * 64);
        const int cgi = it / (NKT * 64), kt = rem >> 6, lane = rem & 63;
        const int col = cgi * 16 + (lane & 15);
        const int k0 = kt * 32 + (lane >> 4) * 8;
        _Float16 o[8];
        for (int j = 0; j < 8; ++j) {
            const int k = k0 + j;
            float wv = 0.f;
            if (col < 160) {
                if (col < HDIM && k < SDIM) wv = sW1[(size_t)k * HDIM + col];
            } else if (col < 320) {
                const int cj = col - 160;
                if (cj < HDIM && k < SDIM) wv = sW1[(size_t)(SDIM + k) * HDIM + cj];
            } else if (col < 480) {
                const int cj = col - 320;
                if (cj < HDIM && k >= SDIM) wv = sW1[(size_t)(SDIM + k) * HDIM + cj]; // rows 2048+(k-1024)
            } else if (col >= 512) {
                const int cj = col - 512;
                if (cj < HDIM && k < SDIM) wv = aW1[(size_t)k * HDIM + cj];
            }
            o[j] = (_Float16)wv;
        }
        *(uint4*)(Wpk + ((size_t)((size_t)cgi * NKT + kt) * 64 + lane) * 8) = *(uint4*)o;
        return;
    }
    it -= ITEMS_W;
    if (it < ITEMS_W2 + ITEMS_A2) {
        const bool is_a = (it >= ITEMS_W2);
        const int li = is_a ? (it - ITEMS_W2) : it;
        const float* src = is_a ? aW2 : sW2;
        _Float16* dst = is_a ? A2pk : W2pk;
        const int tk = li >> 6, lane = li & 63;          // tk = ct*5+ks (0..49)
        const int col = (tk / 5) * 16 + (lane & 15);
        const int k0 = (tk % 5) * 32 + (lane >> 4) * 8;
        _Float16 o[8];
        for (int j = 0; j < 8; ++j) {
            const int k = k0 + j;
            float wv = (col < HDIM && k < HDIM) ? src[(size_t)k * HDIM + col] : 0.f;
            o[j] = (_Float16)wv;
        }
        *(uint4*)(dst + ((size_t)tk * 64 + lane) * 8) = *(uint4*)o;
    }
}

// ---------------------------------------------------------------------------
// k_proj (R10): ONE uniform GEMM — the attn layer-1 columns are folded in as
// live col-groups 30..39 (actual cg 32..41). 640 blocks = 64 bM x 10 bN,
// 32x32 per wave, R4 depth-1 register pipeline, NO LDS, no heavy pole.
// K-ranges: bN<=4 (P1/P2) kt[0,32); bN 5,6 (PE) kt[32,48); bN 7 (PE+attn
// mix) kt[0,48) — Wpk zeros make out-of-segment MFMAs exact +0; bN 8,9
// (attn) kt[0,32). Attn cols epilogue: relu(acc+ab1) -> AH1h (layer-1 out).
// Same per-acc kt order as before -> bit-identical outputs.
// ---------------------------------------------------------------------------
__global__ __launch_bounds__(256) void k_proj(
    const _Float16* __restrict__ Apk, const _Float16* __restrict__ Wpk,
    const float* __restrict__ ab1,
    _Float16* __restrict__ P1h, _Float16* __restrict__ P2h,
    _Float16* __restrict__ PEh, _Float16* __restrict__ AH1h)
{
    const int bid = blockIdx.x;
    const int tid = threadIdx.x;
    const int w = tid >> 6, lane = tid & 63;
    const int quad = lane >> 4, l16 = lane & 15;

    const int bM = bid & 63, bN = bid >> 6;            // bN in [0,10)
    const int wm = w & 1, wn = w >> 1;
    const int gbase = bM * 4 + wm * 2;
    const int cgl = bN * 4 + wn * 2;                   // live col-group base
    const int cga0 = cgl + ((cgl >= 30) ? 2 : 0);      // actual cg (skip pad)
    const int cga1 = (cgl + 1) + (((cgl + 1) >= 30) ? 2 : 0);
    const int kt0 = (bN == 5 || bN == 6) ? 32 : 0;
    const int kt1 = (bN >= 5 && bN <= 7) ? 48 : 32;    // lengths 32/16/48: %4==0

    ffrag acc[2][2];
#pragma unroll
    for (int t = 0; t < 2; ++t)
#pragma unroll
        for (int u = 0; u < 2; ++u) acc[t][u] = (ffrag){0.f, 0.f, 0.f, 0.f};

    const _Float16* a0p = Apk + ((size_t)(gbase + 0) * NKT) * 512 + lane * 8;
    const _Float16* a1p = Apk + ((size_t)(gbase + 1) * NKT) * 512 + lane * 8;
    const _Float16* b0p = Wpk + ((size_t)cga0 * NKT) * 512 + lane * 8;
    const _Float16* b1p = Wpk + ((size_t)cga1 * NKT) * 512 + lane * 8;

    // 2-set modulo-scheduled pipeline; all staging indices compile-time.
    hfrag Ax0[2], Ax1[2], Bx0[2], Bx1[2];
    hfrag Ay0[2], Ay1[2], By0[2], By1[2];

#define LOADB(A0_, A1_, B0_, B1_, kb)                                       \
    _Pragma("unroll")                                                       \
    for (int u_ = 0; u_ < 2; ++u_) {                                        \
        A0_[u_] = *(const hfrag*)(a0p + (size_t)((kb) + u_) * 512);         \
        A1_[u_] = *(const hfrag*)(a1p + (size_t)((kb) + u_) * 512);         \
        B0_[u_] = *(const hfrag*)(b0p + (size_t)((kb) + u_) * 512);         \
        B1_[u_] = *(const hfrag*)(b1p + (size_t)((kb) + u_) * 512);         \
    }
#define MFMAB(A0_, A1_, B0_, B1_)                                           \
    _Pragma("unroll")                                                       \
    for (int u_ = 0; u_ < 2; ++u_) {                                        \
        acc[0][0] = MFMA_(A0_[u_], B0_[u_], acc[0][0]);                     \
        acc[1][0] = MFMA_(A1_[u_], B0_[u_], acc[1][0]);                     \
        acc[0][1] = MFMA_(A0_[u_], B1_[u_], acc[0][1]);                     \
        acc[1][1] = MFMA_(A1_[u_], B1_[u_], acc[1][1]);                     \
    }

    LOADB(Ax0, Ax1, Bx0, Bx1, kt0);
    for (int kb = kt0; kb < kt1; kb += 4) {
        LOADB(Ay0, Ay1, By0, By1, kb + 2);
        MFMAB(Ax0, Ax1, Bx0, Bx1);
        if (kb + 4 < kt1) LOADB(Ax0, Ax1, Bx0, Bx1, kb + 4);
        MFMAB(Ay0, Ay1, By0, By1);
    }
#undef LOADB
#undef MFMAB

#pragma unroll
    for (int t = 0; t < 2; ++t)
#pragma unroll
        for (int u = 0; u < 2; ++u) {
            const int cga = u ? cga1 : cga0;
#pragma unroll
            for (int r = 0; r < 4; ++r) {
                const int row = (gbase + t) * 16 + quad * 4 + r;
                if (cga < 30) {                        // raw projection halves
                    const int col = cga * 16 + l16;
                    const _Float16 hv = (_Float16)acc[t][u][r];
                    if (col < 160)      P1h[(size_t)row * SEG + col] = hv;
                    else if (col < 320) P2h[(size_t)row * SEG + (col - 160)] = hv;
                    else                PEh[(size_t)row * SEG + (col - 320)] = hv;
                } else {                               // attn layer-1 epilogue
                    const int colA = (cga - 32) * 16 + l16;
                    const float b1 = (colA < HDIM) ? ab1[colA] : 0.f;
                    AH1h[(size_t)row * SEG + colA] =
                        (_Float16)fmaxf(acc[t][u][r] + b1, 0.f);
                }
            }
        }
}

// ---------------------------------------------------------------------------
// span (R10): adds the tiny attn layers 2+3 (per-block recompute, identical
// op order -> bit-identical attns) before softmax. Stages AH1s (48 rows) and
// PEs (41 rows) in LDS; waves 0-2 finish attn -> att[48]; softmax; phase1;
// phase2 as before. LDS 51.7 KB -> 3 blocks/CU.
// ---------------------------------------------------------------------------
__global__ __launch_bounds__(256) void span_kernel(
    const _Float16* __restrict__ AH1h, const _Float16* __restrict__ P1h,
    const _Float16* __restrict__ P2h, const _Float16* __restrict__ PEh,
    const float* __restrict__ sb1, const _Float16* __restrict__ W2pk,
    const float* __restrict__ sb2, const float* __restrict__ sW3,
    const float* __restrict__ sb3,
    const _Float16* __restrict__ A2pk, const float* __restrict__ ab2,
    const float* __restrict__ aW3, const float* __restrict__ ab3,
    float* __restrict__ out)
{
    const int pairI = blockIdx.x % 5;         // 0..4 (interleaved heavy/light)
    const int mChunk = blockIdx.x / 5;        // 0..127
    const int n0 = 2 * pairI + 1, n1 = n0 + 1;
    const int Mn0 = LTOK - n0 + 1, Mn1 = Mn0 - 1;
    const int m0 = mChunk * 32;
    const int offn0 = (n0 - 1) * LTOK - ((n0 - 1) * (n0 - 2)) / 2;
    const int offn1 = offn0 + Mn0;

    const int tid = threadIdx.x;
    const int w = tid >> 6, lane = tid & 63, quad = lane >> 4, l16 = lane & 15;

    __shared__ __align__(16) _Float16 h1h[2][32 * K2];   // 20480 B
    __shared__ __align__(16) _Float16 PEs[41 * SEG];     // 13120 B
    __shared__ __align__(16) _Float16 AH1s[48 * SEG];    // 15360 B
    __shared__ float att[48];                            // 192 B
    __shared__ float wgt[2][32][MAXN];                   // 2560 B

    // stage PE rows m0..m0+40 and AH1 rows m0..m0+47 (row-clamped) into LDS
    for (int t = tid; t < 41 * (SEG / 8); t += 256) {
        const int rr = t / (SEG / 8), cc = t % (SEG / 8);
        const int srcRow = min(m0 + rr, LTOK - 1);
        *(uint4*)&PEs[rr * SEG + cc * 8] =
            *(const uint4*)(PEh + (size_t)srcRow * SEG + cc * 8);
    }
    for (int t = tid; t < 48 * (SEG / 8); t += 256) {
        const int rr = t / (SEG / 8), cc = t % (SEG / 8);
        const int srcRow = min(m0 + rr, LTOK - 1);
        *(uint4*)&AH1s[rr * SEG + cc * 8] =
            *(const uint4*)(AH1h + (size_t)srcRow * SEG + cc * 8);
    }
    __syncthreads();

    // attn finish: waves 0..2 -> local tokens w*16..w*16+15 (identical op
    // order to the original layers-2+3 path -> bit-identical attns)
    if (w < 3) {
        hfrag af[5];
#pragma unroll
        for (int ks = 0; ks < 5; ++ks)
            af[ks] = *(const hfrag*)&AH1s[(w * 16 + l16) * SEG + ks * 32 + quad * 8];

        float part[4] = {0.f, 0.f, 0.f, 0.f};
        for (int ct = 0; ct < 10; ++ct) {
            ffrag a2 = (ffrag){0.f, 0.f, 0.f, 0.f};
#pragma unroll
            for (int ks = 0; ks < 5; ++ks) {
                const hfrag fb = *(const hfrag*)(
                    A2pk + ((size_t)(ct * 5 + ks) * 64 + lane) * 8);
                a2 = MFMA_(af[ks], fb, a2);
            }
            const int col = ct * 16 + l16;
            const float s2 = (col < HDIM) ? ab2[col] : 0.f;
            const float s3 = (col < HDIM) ? aW3[col] : 0.f;
#pragma unroll
            for (int r = 0; r < 4; ++r) part[r] += fmaxf(a2[r] + s2, 0.f) * s3;
        }
#pragma unroll
        for (int off = 1; off < 16; off <<= 1) {
#pragma unroll
            for (int r = 0; r < 4; ++r) part[r] += __shfl_xor(part[r], off, 64);
        }
        if (l16 == 0) {
            const float b3 = ab3[0];
#pragma unroll
            for (int r = 0; r < 4; ++r)
                att[w * 16 + quad * 4 + r] = part[r] + b3;
        }
    }
    __syncthreads();

    if (tid < 64) {
        const int q = tid >> 5, r = tid & 31;
        const int n = q ? n1 : n0;
        const int Mn = q ? Mn1 : Mn0;
        const int m = m0 + r;
        if (m < Mn) {
            const int jcap = LTOK - 1 - m0;            // local clamp bound
            float av[MAXN];
#pragma unroll
            for (int j = 0; j < MAXN; ++j)
                av[j] = att[min(r + j, jcap)];         // == attns[min(m+j,L-1)]
            float mx = -1e30f;
            for (int j = 0; j < n; ++j) mx = fmaxf(mx, av[j]);
            float tp[MAXN]; float s = 0.f;
            for (int j = 0; j < n; ++j) { tp[j] = expf(av[j] - mx); s += tp[j]; }
            const float inv = 1.f / s;
            for (int j = 0; j < MAXN; ++j) wgt[q][r][j] = (j < n) ? tp[j] * inv : 0.f;
        } else {
            for (int j = 0; j < MAXN; ++j) wgt[q][r][j] = 0.f;
        }
    }
    __syncthreads();

    // phase 1: 32 rows x 20 col-chunks (8 cols), BOTH n per item; full unroll
    for (int item = tid; item < 32 * (K2 / 8); item += 256) {
        const int r = item / (K2 / 8), cc = item % (K2 / 8);
        const int c0 = cc * 8;
        const int mm = m0 + r;                       // < 4096 always
        const hfrag p1  = *(const hfrag*)(P1h + (size_t)mm * SEG + c0);
        const hfrag p2a = *(const hfrag*)(P2h + (size_t)min(mm + n0 - 1, LTOK - 1) * SEG + c0);
        const hfrag p2b = *(const hfrag*)(P2h + (size_t)min(mm + n0, LTOK - 1) * SEG + c0);
        float b1v[8];
#pragma unroll
        for (int e = 0; e < 8; ++e)
            b1v[e] = (c0 + e < HDIM) ? sb1[c0 + e] : 0.f;
        float a0[8], a1[8];
#pragma unroll
        for (int e = 0; e < 8; ++e) {
            a0[e] = (float)p1[e] + (float)p2a[e] + b1v[e];
            a1[e] = (float)p1[e] + (float)p2b[e] + b1v[e];
        }
#pragma unroll
        for (int j = 0; j < MAXN; ++j) {             // weights 0 past n -> exact no-op
            const hfrag pe = *(const hfrag*)&PEs[(r + j) * SEG + c0];
            const float w0j = wgt[0][r][j];
            const float w1j = wgt[1][r][j];
#pragma unroll
            for (int e = 0; e < 8; ++e) {
                const float pv = (float)pe[e];
                a0[e] = fmaf(w0j, pv, a0[e]);
                a1[e] = fmaf(w1j, pv, a1[e]);
            }
        }
        _Float16 o0[8], o1[8];
#pragma unroll
        for (int e = 0; e < 8; ++e) {
            const bool live = (c0 + e < HDIM);
            o0[e] = live ? (_Float16)fmaxf(a0[e], 0.f) : (_Float16)0.f;
            o1[e] = live ? (_Float16)fmaxf(a1[e], 0.f) : (_Float16)0.f;
        }
        *(uint4*)&h1h[0][r * K2 + c0] = *(uint4*)o0;
        *(uint4*)&h1h[1][r * K2 + c0] = *(uint4*)o1;
    }
    __syncthreads();

    // phase 2: wave w -> side q = w>>1, row-group rg = w&1 (16 rows)
    const int q = w >> 1, rg = w & 1;
    const int Mq = q ? Mn1 : Mn0;
    const int offq = q ? offn1 : offn0;

    hfrag af2[5];
#pragma unroll
    for (int ks = 0; ks < 5; ++ks)
        af2[ks] = *(const hfrag*)&h1h[q][(rg * 16 + l16) * K2 + ks * 32 + quad * 8];

    float part2[4] = {0.f, 0.f, 0.f, 0.f};
    for (int ct = 0; ct < 10; ++ct) {
        ffrag acc = (ffrag){0.f, 0.f, 0.f, 0.f};
#pragma unroll
        for (int ks = 0; ks < 5; ++ks) {
            const hfrag fb = *(const hfrag*)(
                W2pk + ((size_t)(ct * 5 + ks) * 64 + lane) * 8);
            acc = MFMA_(af2[ks], fb, acc);
        }
        const int col = ct * 16 + l16;
        const float s2 = (col < HDIM) ? sb2[col] : 0.f;
        const float s3 = (col < HDIM) ? sW3[col] : 0.f;
#pragma unroll
        for (int r = 0; r < 4; ++r) part2[r] += fmaxf(acc[r] + s2, 0.f) * s3;
    }

#pragma unroll
    for (int off = 1; off < 16; off <<= 1) {
#pragma unroll
        for (int r = 0; r < 4; ++r) part2[r] += __shfl_xor(part2[r], off, 64);
    }
    if (l16 == 0) {
        const float b3 = sb3[0];
#pragma unroll
        for (int r = 0; r < 4; ++r) {
            const int lr = rg * 16 + quad * 4 + r;   // 0..31
            if (m0 + lr < Mq) out[offq + m0 + lr] = part2[r] + b3;
        }
    }
}

// ---------------------------------------------------------------------------
extern "C" void kernel_launch(void* const* d_in, const int* in_sizes, int n_in,
                              void* d_out, int out_size, void* d_ws, size_t ws_size,
                              hipStream_t stream) {
    const float* embeds = (const float*)d_in[0];
    const float* states = (const float*)d_in[1];
    const float* aW1 = (const float*)d_in[2];
    const float* ab1 = (const float*)d_in[3];
    const float* aW2 = (const float*)d_in[4];
    const float* ab2 = (const float*)d_in[5];
    const float* aW3 = (const float*)d_in[6];
    const float* ab3 = (const float*)d_in[7];
    const float* sW1 = (const float*)d_in[8];
    const float* sb1 = (const float*)d_in[9];
    const float* sW2 = (const float*)d_in[10];
    const float* sb2 = (const float*)d_in[11];
    const float* sW3 = (const float*)d_in[12];
    const float* sb3 = (const float*)d_in[13];
    float* out = (float*)d_out;

    // ws: fp16 P1h | P2h | PEh | AH1h (SEG rows) | Apk | Wpk | W2pk | A2pk
    _Float16* P1h  = (_Float16*)d_ws;
    _Float16* P2h  = P1h + (size_t)LTOK * SEG;
    _Float16* PEh  = P2h + (size_t)LTOK * SEG;
    _Float16* AH1h = PEh + (size_t)LTOK * SEG;
    _Float16* Apk  = AH1h + (size_t)LTOK * SEG;
    _Float16* Wpk  = Apk + (size_t)ITEMS_A * 8;
    _Float16* W2pk = Wpk + (size_t)ITEMS_W * 8;
    _Float16* A2pk = W2pk + (size_t)ITEMS_W2 * 8;
    // total ~20.3 MB

    prep_kernel<<<ITEMS_TOT / 256, 256, 0, stream>>>(
        embeds, states, aW1, aW2, sW1, sW2, Apk, Wpk, W2pk, A2pk);
    k_proj<<<640, 256, 0, stream>>>(
        Apk, Wpk, ab1, P1h, P2h, PEh, AH1h);
    span_kernel<<<640, 256, 0, stream>>>(
        AH1h, P1h, P2h, PEh, sb1, W2pk, sb2, sW3, sb3,
        A2pk, ab2, aW3, ab3, out);
}